// Round 2
// baseline (612.947 us; speedup 1.0000x reference)
//
#include <hip/hip_runtime.h>
#include <math.h>

namespace {
constexpr int SEQ = 2048;
constexpr int NH  = 16;
constexpr int DH  = 128;
constexpr int QB  = 32;
constexpr int KB  = 64;

typedef float f32x4 __attribute__((ext_vector_type(4)));
typedef short s16x8 __attribute__((ext_vector_type(8)));
typedef short s16x4 __attribute__((ext_vector_type(4)));

__device__ __forceinline__ unsigned short f2bf(float f) {
  unsigned u = __builtin_bit_cast(unsigned, f);
  return (unsigned short)((u + 0x7fffu + ((u >> 16) & 1u)) >> 16);
}
__device__ __forceinline__ int imin(int a, int b) { return a < b ? a : b; }
}

// One block: (b, head-pair hp, q-tile of 32 rows). 4 waves:
//   wave = (h in {0,1}, qt in {0,1}) -> head hp*2+h, q rows q0+qt*16..+15
// Swapped QK^T (mfma(K, Q^T)) keeps P in registers; PV via 16x16x16 MFMA
// whose A-frag mapping (k = kb*4+j) matches the S^T C-frag ownership exactly.
__global__ __launch_bounds__(256, 2) void diffattn_kernel(
    const float* __restrict__ qg, const float* __restrict__ kgl, const float* __restrict__ vg,
    const float* __restrict__ lq1, const float* __restrict__ lk1,
    const float* __restrict__ lq2, const float* __restrict__ lk2,
    const float* __restrict__ wsub, const int* __restrict__ amask,  // bool -> int32 on upload
    float* __restrict__ outp, float lambda_init)
{
  __shared__ __align__(16) unsigned char smem[66560];
  unsigned char* Klds = smem;           // [2 heads][64 rows][128 bf16] rows 256B, XOR-swizzled
  unsigned char* VT   = smem + 32768;   // [256 cols][64 k] bf16, rows 128B, XOR-swizzled
  float* Olds = (float*)smem;           // epilogue alias: [2][32][260] fp32

  const int tid  = (int)threadIdx.x;
  const int lane = tid & 63;
  const int wid  = tid >> 6;
  const int h    = wid >> 1;
  const int qt   = wid & 1;
  const int lr   = lane & 15;
  const int kb   = lane >> 4;

  // bid -> (hp, b, qtile): hp in low 3 bits pins a head-pair to one XCD (L2
  // locality for its 3MB KV working set); qtile reversed so heavy blocks first.
  const int bid   = (int)blockIdx.x;
  const int hp    = bid & 7;
  const int rest  = bid >> 3;
  const int b     = rest >> 6;
  const int qtile = 63 - (rest & 63);
  const int q0    = qtile * QB;

  // lambda_full = exp(sum lq1*lk1) - exp(sum lq2*lk2) + lambda_init (per-wave)
  float s1 = lq1[lane]*lk1[lane] + lq1[lane+64]*lk1[lane+64];
  float s2 = lq2[lane]*lk2[lane] + lq2[lane+64]*lk2[lane+64];
  #pragma unroll
  for (int o = 32; o; o >>= 1) { s1 += __shfl_xor(s1, o); s2 += __shfl_xor(s2, o); }
  const float lambda_full = expf(s1) - expf(s2) + lambda_init;

  // Q fragments, pre-scaled by log2(e)/sqrt(D) (exp2-domain softmax)
  const float qscale = 1.44269504088896f / sqrtf((float)DH);
  s16x8 qf[4];
  {
    const int qrow = q0 + qt*16 + lr;
    const float* qp = qg + (((long)b*SEQ + qrow)*NH + hp*2 + h)*DH;
    #pragma unroll
    for (int ds = 0; ds < 4; ++ds) {
      const float4 a0 = *(const float4*)(qp + ds*32 + kb*8);
      const float4 a1 = *(const float4*)(qp + ds*32 + kb*8 + 4);
      s16x8 f;
      f[0]=(short)f2bf(a0.x*qscale); f[1]=(short)f2bf(a0.y*qscale);
      f[2]=(short)f2bf(a0.z*qscale); f[3]=(short)f2bf(a0.w*qscale);
      f[4]=(short)f2bf(a1.x*qscale); f[5]=(short)f2bf(a1.y*qscale);
      f[6]=(short)f2bf(a1.z*qscale); f[7]=(short)f2bf(a1.w*qscale);
      qf[ds] = f;
    }
  }

  f32x4 acc[16];
  #pragma unroll
  for (int i = 0; i < 16; ++i) acc[i] = (f32x4){0.f,0.f,0.f,0.f};
  float m_run = -3.0e38f, l_run = 0.f;

  const int n_tiles = qtile/2 + 1;
  for (int it = 0; it < n_tiles; ++it) {
    const int k0 = it * KB;
    __syncthreads();   // prev iter's LDS reads done before restage

    // ---- stage K (both heads), bf16, row-major + XOR swizzle ----
    #pragma unroll
    for (int i = 0; i < 16; ++i) {
      const int idx = tid + i*256;              // 4096 float4-chunks
      const int hh  = idx >> 11;
      const int row = (idx >> 5) & 63;
      const int dc  = idx & 31;
      const int rg  = imin(k0 + row, SEQ-1);
      const float4 val = *(const float4*)(kgl + (((long)b*SEQ + rg)*NH + hp*2 + hh)*DH + dc*4);
      s16x4 pk = { (short)f2bf(val.x), (short)f2bf(val.y),
                   (short)f2bf(val.z), (short)f2bf(val.w) };
      *(s16x4*)(Klds + hh*16384 + row*256 + ((dc*8) ^ ((row&7)<<4))) = pk;
    }
    // ---- stage V transposed: VT[c][k] (c: 0..127 head even, 128..255 odd) ----
    {
      const long rowstride = (long)NH * DH;
      #pragma unroll
      for (int cg = 0; cg < 4; ++cg) {
        const int c    = cg*64 + lane;
        const int head = hp*2 + (c >> 7);
        const float* vcol = vg + ((long)b*SEQ*NH + head)*DH + (c & 127);
        const int sw = (c & 7) << 4;
        #pragma unroll
        for (int kg2 = 0; kg2 < 2; ++kg2) {
          const int kkb = wid*16 + kg2*8;
          unsigned short t[8];
          #pragma unroll
          for (int j = 0; j < 8; ++j) {
            const int rg = imin(k0 + kkb + j, SEQ-1);
            t[j] = f2bf(vcol[(long)rg * rowstride]);
          }
          s16x8 pk = { (short)t[0],(short)t[1],(short)t[2],(short)t[3],
                       (short)t[4],(short)t[5],(short)t[6],(short)t[7] };
          *(s16x8*)(VT + c*128 + ((kkb*2) ^ sw)) = pk;
        }
      }
    }
    __syncthreads();

    // padding-mask ballot: bit i = key k0+i valid (mask uploaded as int32)
    const int kcl = imin(k0 + lane, SEQ-1);
    const unsigned long long bm =
        __ballot((k0 + lane < SEQ) && (amask[b*SEQ + kcl] != 0));

    // ---- S^T = K . Q^T  (16x16x32 bf16) ----
    const int qgrow = q0 + qt*16 + lr;
    f32x4 st[4];
    #pragma unroll
    for (int kt = 0; kt < 4; ++kt) {
      const int row = kt*16 + lr;
      const unsigned char* kbase = Klds + h*16384 + row*256;
      const int sw = (row & 7) << 4;
      f32x4 c = {0.f,0.f,0.f,0.f};
      #pragma unroll
      for (int ds = 0; ds < 4; ++ds) {
        const s16x8 af = *(const s16x8*)(kbase + ((ds*64 + kb*16) ^ sw));
        c = __builtin_amdgcn_mfma_f32_16x16x32_bf16(af, qf[ds], c, 0, 0, 0);
      }
      st[kt] = c;
    }

    // ---- online softmax (exp2 domain); lane owns q-row lr, k = kt*16+kb*4+r ----
    const bool needmask = !(((k0 + KB - 1) <= (q0 + qt*16)) && (bm == ~0ull));
    float mx = -3.0e38f;
    float p[4][4];
    #pragma unroll
    for (int kt = 0; kt < 4; ++kt)
      #pragma unroll
      for (int r = 0; r < 4; ++r) {
        float sv = st[kt][r];
        if (needmask) {
          const int klo = kt*16 + kb*4 + r;
          const bool ok = ((k0 + klo) <= qgrow) && ((bm >> klo) & 1ull);
          sv = ok ? sv : -3.0e38f;
          st[kt][r] = sv;
        }
        mx = fmaxf(mx, sv);
      }
    mx = fmaxf(mx, __shfl_xor(mx, 16));
    mx = fmaxf(mx, __shfl_xor(mx, 32));
    const float mnew = fmaxf(m_run, mx);
    const float fac  = __builtin_amdgcn_exp2f(m_run - mnew);
    float lsum = 0.f;
    #pragma unroll
    for (int kt = 0; kt < 4; ++kt)
      #pragma unroll
      for (int r = 0; r < 4; ++r) {
        const float pv = __builtin_amdgcn_exp2f(st[kt][r] - mnew);
        p[kt][r] = pv; lsum += pv;
      }
    lsum += __shfl_xor(lsum, 16); lsum += __shfl_xor(lsum, 32);
    l_run = l_run * fac + lsum;
    m_run = mnew;

    // rescale O by fac of its C-frag rows (q = kb*4+r)
    float fq[4];
    #pragma unroll
    for (int r = 0; r < 4; ++r) fq[r] = __shfl(fac, kb*4 + r);
    #pragma unroll
    for (int ct = 0; ct < 16; ++ct) {
      acc[ct][0]*=fq[0]; acc[ct][1]*=fq[1]; acc[ct][2]*=fq[2]; acc[ct][3]*=fq[3];
    }

    // pack P (A-frag of 16x16x16: lane holds P[lr][kt*16+kb*4+j] = p[kt][j])
    s16x4 pa[4];
    #pragma unroll
    for (int kt = 0; kt < 4; ++kt) {
      s16x4 t = { (short)f2bf(p[kt][0]), (short)f2bf(p[kt][1]),
                  (short)f2bf(p[kt][2]), (short)f2bf(p[kt][3]) };
      pa[kt] = t;
    }

    // ---- O += P . V256  (16x16x16 bf16, B-frag = contiguous ds_read from VT) ----
    #pragma unroll
    for (int ct = 0; ct < 16; ++ct) {
      const int c = ct*16 + lr;
      const unsigned char* vrow = VT + c*128;
      const int sw = (c & 7) << 4;
      #pragma unroll
      for (int kt = 0; kt < 4; ++kt) {
        const s16x4 bf = *(const s16x4*)(vrow + ((kt*32 + kb*8) ^ sw));
        acc[ct] = __builtin_amdgcn_mfma_f32_16x16x16bf16_1k(pa[kt], bf, acc[ct], 0, 0, 0);
      }
    }
  }

  // ---- epilogue: normalize, exchange via LDS, combine, RMS-norm, store ----
  __syncthreads();   // all waves done with K/V LDS before aliasing with Olds
  float lqv[4];
  #pragma unroll
  for (int r = 0; r < 4; ++r) lqv[r] = 1.f / __shfl(l_run, kb*4 + r);
  #pragma unroll
  for (int ct = 0; ct < 16; ++ct) {
    const int orow = h*32 + qt*16 + kb*4;
    #pragma unroll
    for (int r = 0; r < 4; ++r)
      Olds[(orow + r)*260 + ct*16 + lr] = acc[ct][r] * lqv[r];
  }
  __syncthreads();

  const int row   = tid >> 3;          // 0..31
  const int cbase = (tid & 7) * 32;
  float ov[32];
  float ss = 0.f;
  #pragma unroll
  for (int i = 0; i < 32; i += 4) {
    const float4 oa = *(const float4*)&Olds[row*260 + cbase + i];
    const float4 ob = *(const float4*)&Olds[(32 + row)*260 + cbase + i];
    ov[i+0] = oa.x - lambda_full*ob.x;
    ov[i+1] = oa.y - lambda_full*ob.y;
    ov[i+2] = oa.z - lambda_full*ob.z;
    ov[i+3] = oa.w - lambda_full*ob.w;
    ss += ov[i+0]*ov[i+0] + ov[i+1]*ov[i+1] + ov[i+2]*ov[i+2] + ov[i+3]*ov[i+3];
  }
  ss += __shfl_xor(ss, 1); ss += __shfl_xor(ss, 2); ss += __shfl_xor(ss, 4);
  const float rms = rsqrtf(ss * (1.0f/256.0f) + 1e-5f);
  const float fin = 1.0f - lambda_init;
  float* op = outp + (((long)b*SEQ + q0 + row)*8 + hp)*256 + cbase;
  #pragma unroll
  for (int i = 0; i < 32; i += 4) {
    const float4 w4 = *(const float4*)(wsub + cbase + i);
    float4 o4;
    o4.x = ov[i+0]*rms*w4.x*fin;
    o4.y = ov[i+1]*rms*w4.y*fin;
    o4.z = ov[i+2]*rms*w4.z*fin;
    o4.w = ov[i+3]*rms*w4.w*fin;
    *(float4*)(op + i) = o4;
  }
}

extern "C" void kernel_launch(void* const* d_in, const int* in_sizes, int n_in,
                              void* d_out, int out_size, void* d_ws, size_t ws_size,
                              hipStream_t stream) {
  (void)in_sizes; (void)n_in; (void)out_size; (void)d_ws; (void)ws_size;
  const float lambda_init = (float)(0.8 - 0.6 * exp(-0.3 * (12 - 1)));
  diffattn_kernel<<<dim3(1024), dim3(256), 0, stream>>>(
      (const float*)d_in[0], (const float*)d_in[1], (const float*)d_in[2],
      (const float*)d_in[3], (const float*)d_in[4], (const float*)d_in[5],
      (const float*)d_in[6], (const float*)d_in[7],
      (const int*)d_in[8],
      (float*)d_out, lambda_init);
}

// Round 3
// 321.327 us; speedup vs baseline: 1.9076x; 1.9076x over previous
//
#include <hip/hip_runtime.h>
#include <math.h>

namespace {
constexpr int SEQ = 2048;
constexpr int NH  = 16;
constexpr int DH  = 128;
constexpr int QB  = 32;
constexpr int KBT = 32;          // K-tile rows per iteration

typedef float f32x4 __attribute__((ext_vector_type(4)));
typedef short s16x8 __attribute__((ext_vector_type(8)));
typedef short s16x4 __attribute__((ext_vector_type(4)));
typedef unsigned short u16;

__device__ __forceinline__ u16 f2bf(float f) {
  unsigned u = __builtin_bit_cast(unsigned, f);
  return (u16)((u + 0x7fffu + ((u >> 16) & 1u)) >> 16);
}

__device__ __forceinline__ void gload16(const void* g, void* l) {
  __builtin_amdgcn_global_load_lds((const __attribute__((address_space(1))) void*)g,
                                   (__attribute__((address_space(3))) void*)l, 16, 0, 0);
}
}

// ---------------- prep: K -> bf16 [b][hp][h][k][128]; V -> bf16 transposed
// [b][hp][c=256][k=2048]  (c = h*128 + d). One block per (b, head, ktile64).
__global__ __launch_bounds__(256) void prep_kernel(
    const float* __restrict__ kgl, const float* __restrict__ vg,
    u16* __restrict__ kb16, u16* __restrict__ vt16)
{
  __shared__ u16 vlds[64][132];
  const int tid = threadIdx.x, bid = blockIdx.x;
  const int kt = bid & 31, head = (bid >> 5) & 15, b = bid >> 9;
  const int k0 = kt * 64, hp = head >> 1, hh = head & 1;
  const float* ksrc = kgl + (((long)b*SEQ + k0)*NH + head)*DH;
  const float* vsrc = vg  + (((long)b*SEQ + k0)*NH + head)*DH;
  u16* kdst = kb16 + (((long)((b*8+hp)*2 + hh)*SEQ) + k0)*DH;
  #pragma unroll
  for (int i = 0; i < 8; ++i) {
    const int idx = tid + i*256, row = idx >> 5, c4 = idx & 31;
    const float4 v = *(const float4*)(ksrc + (long)row*(NH*DH) + c4*4);
    ushort4 pk = { f2bf(v.x), f2bf(v.y), f2bf(v.z), f2bf(v.w) };
    *(ushort4*)(kdst + row*DH + c4*4) = pk;
    const float4 w = *(const float4*)(vsrc + (long)row*(NH*DH) + c4*4);
    ushort4 pw = { f2bf(w.x), f2bf(w.y), f2bf(w.z), f2bf(w.w) };
    *(ushort4*)(&vlds[row][c4*4]) = pw;
  }
  __syncthreads();
  const int c = tid >> 1, half = tid & 1;
  u16* vdst = vt16 + (((long)(b*8+hp)*256) + hh*128 + c)*SEQ + k0 + half*32;
  #pragma unroll
  for (int j = 0; j < 8; ++j) {
    ushort4 pk = { vlds[half*32 + j*4 + 0][c], vlds[half*32 + j*4 + 1][c],
                   vlds[half*32 + j*4 + 2][c], vlds[half*32 + j*4 + 3][c] };
    *(ushort4*)(vdst + j*4) = pk;
  }
}

// ---------------- main: block = (hp, qtile-pair p, b). 4 waves (h, qt).
// Double-buffered global_load_lds staging; swapped QK^T; in-register softmax.
__global__ __launch_bounds__(256, 2) void diffattn_kernel(
    const float* __restrict__ qg,
    const u16* __restrict__ kb16, const u16* __restrict__ vt16,
    const float* __restrict__ lq1, const float* __restrict__ lk1,
    const float* __restrict__ lq2, const float* __restrict__ lk2,
    const float* __restrict__ wsub, const int* __restrict__ amask,
    float* __restrict__ outp, float lambda_init)
{
  // Kbuf[s] @ s*16384      : [h][32 rows][256B], 16B-chunk j ^= (row&7)
  // Vbuf[s] @ 32768+s*16384: [256 c][64B],       16B-chunk j ^= (c&3)
  // OBt (epilogue alias @0): [256 c][128B fp32], 16B-chunk j ^= (c&7)
  __shared__ __align__(16) unsigned char smem[65536];
  const int tid = threadIdx.x, lane = tid & 63, wid = tid >> 6;
  const int h = wid >> 1, qt = wid & 1, lr = lane & 15, kb = lane >> 4;
  const int bid = blockIdx.x;
  const int hp = bid & 7, rest = bid >> 3, p = rest & 31, b = rest >> 5;

  float s1 = lq1[lane]*lk1[lane] + lq1[lane+64]*lk1[lane+64];
  float s2 = lq2[lane]*lk2[lane] + lq2[lane+64]*lk2[lane+64];
  #pragma unroll
  for (int o = 32; o; o >>= 1) { s1 += __shfl_xor(s1, o); s2 += __shfl_xor(s2, o); }
  const float lambda_full = expf(s1) - expf(s2) + lambda_init;

  // stage source bases (per-lane, k0 = 0), swizzle pre-applied to source
  const int srow = tid >> 4, sj = tid & 15;
  const int kchunk = sj ^ (srow & 7);
  const u16* kbase = kb16 + ((long)(b*8+hp)*2)*SEQ*DH;
  const u16* kp0 = kbase + (long)srow*DH + kchunk*8;
  const int vc = tid >> 2, vj = tid & 3;
  const u16* vp0 = vt16 + (((long)(b*8+hp)*256) + vc)*SEQ + (vj ^ (vc & 3))*8;

  const float qscale = 1.44269504088896f / sqrtf((float)DH);

  #pragma unroll 1
  for (int qi = 0; qi < 2; ++qi) {
    const int qtile = qi ? (63 - p) : p;
    const int q0 = qtile * QB;
    __syncthreads();                       // LDS reuse vs prev epilogue reads

    s16x8 qf[4];
    {
      const int qrow = q0 + qt*16 + lr;
      const float* qp = qg + (((long)b*SEQ + qrow)*NH + hp*2 + h)*DH;
      #pragma unroll
      for (int ds = 0; ds < 4; ++ds) {
        const float4 a0 = *(const float4*)(qp + ds*32 + kb*8);
        const float4 a1 = *(const float4*)(qp + ds*32 + kb*8 + 4);
        s16x8 f;
        f[0]=(short)f2bf(a0.x*qscale); f[1]=(short)f2bf(a0.y*qscale);
        f[2]=(short)f2bf(a0.z*qscale); f[3]=(short)f2bf(a0.w*qscale);
        f[4]=(short)f2bf(a1.x*qscale); f[5]=(short)f2bf(a1.y*qscale);
        f[6]=(short)f2bf(a1.z*qscale); f[7]=(short)f2bf(a1.w*qscale);
        qf[ds] = f;
      }
    }

    f32x4 acc[16];
    #pragma unroll
    for (int i = 0; i < 16; ++i) acc[i] = (f32x4){0.f,0.f,0.f,0.f};
    float m_run = -3.0e38f, l_run = 0.f;
    const int nt = qtile + 1;
    const int qgrow = q0 + qt*16 + lr;
    const int qmin  = q0 + qt*16;

    // ---- stage tile k0 into buffer s ----
    auto STAGE = [&](int k0, int s) {
      unsigned char* dK = smem + s*16384;
      unsigned char* dV = smem + 32768 + s*16384;
      const u16* ka = kp0 + (long)k0*DH;
      const u16* kbl = ka + (long)SEQ*DH;           // h = 1
      gload16(ka,           dK + tid*16);
      gload16(ka + 16*DH,   dK + tid*16 + 4096);
      gload16(kbl,          dK + tid*16 + 8192);
      gload16(kbl + 16*DH,  dK + tid*16 + 12288);
      const u16* va = vp0 + k0;
      gload16(va,           dV + tid*16);
      gload16(va + 64*SEQ,  dV + tid*16 + 4096);
      gload16(va + 128*SEQ, dV + tid*16 + 8192);
      gload16(va + 192*SEQ, dV + tid*16 + 12288);
    };

    STAGE(0, 0);
    __syncthreads();                       // vmcnt(0) drain: buf0 ready

    for (int t = 0; t < nt; ++t) {
      const int cur = t & 1;
      if (t + 1 < nt) STAGE((t+1)*KBT, cur ^ 1);   // async prefetch
      const int k0 = t * KBT;

      const int mi = amask[b*SEQ + k0 + (lane & 31)];
      const unsigned bm32 = (unsigned)__ballot(mi != 0 && lane < 32);

      // S^T = K . Q^T  (16x16x32 bf16)
      const unsigned char* Kc = smem + cur*16384 + h*8192;
      f32x4 st[2];
      #pragma unroll
      for (int kt2 = 0; kt2 < 2; ++kt2) {
        const int row = kt2*16 + lr;
        const unsigned char* kr = Kc + row*256;
        const int sw = (row & 7) << 4;
        f32x4 c = {0.f,0.f,0.f,0.f};
        #pragma unroll
        for (int ds = 0; ds < 4; ++ds) {
          const s16x8 af = *(const s16x8*)(kr + ((ds*64 + kb*16) ^ sw));
          c = __builtin_amdgcn_mfma_f32_16x16x32_bf16(af, qf[ds], c, 0, 0, 0);
        }
        st[kt2] = c;
      }

      // online softmax (exp2 domain); lane owns q-row lr, k = kt2*16+kb*4+r
      const bool needmask = !((k0 + KBT - 1 <= qmin) && (bm32 == 0xffffffffu));
      float mx = -3.0e38f;
      float pp[2][4];
      #pragma unroll
      for (int kt2 = 0; kt2 < 2; ++kt2)
        #pragma unroll
        for (int r = 0; r < 4; ++r) {
          float sv = st[kt2][r];
          if (needmask) {
            const int klo = kt2*16 + kb*4 + r;
            const bool ok = (k0 + klo <= qgrow) && ((bm32 >> klo) & 1u);
            sv = ok ? sv : -3.0e38f;
            st[kt2][r] = sv;
          }
          mx = fmaxf(mx, sv);
        }
      mx = fmaxf(mx, __shfl_xor(mx, 16));
      mx = fmaxf(mx, __shfl_xor(mx, 32));
      const float mnew = fmaxf(m_run, mx);
      const float fac  = __builtin_amdgcn_exp2f(m_run - mnew);
      float lsum = 0.f;
      #pragma unroll
      for (int kt2 = 0; kt2 < 2; ++kt2)
        #pragma unroll
        for (int r = 0; r < 4; ++r) {
          const float pv = __builtin_amdgcn_exp2f(st[kt2][r] - mnew);
          pp[kt2][r] = pv; lsum += pv;
        }
      lsum += __shfl_xor(lsum, 16); lsum += __shfl_xor(lsum, 32);
      l_run = l_run * fac + lsum;
      m_run = mnew;

      float fq[4];
      #pragma unroll
      for (int r = 0; r < 4; ++r) fq[r] = __shfl(fac, kb*4 + r);
      #pragma unroll
      for (int ct = 0; ct < 16; ++ct) {
        acc[ct][0]*=fq[0]; acc[ct][1]*=fq[1]; acc[ct][2]*=fq[2]; acc[ct][3]*=fq[3];
      }

      s16x4 pa[2];
      #pragma unroll
      for (int kt2 = 0; kt2 < 2; ++kt2) {
        s16x4 tt = { (short)f2bf(pp[kt2][0]), (short)f2bf(pp[kt2][1]),
                     (short)f2bf(pp[kt2][2]), (short)f2bf(pp[kt2][3]) };
        pa[kt2] = tt;
      }

      // O += P . V256 (16x16x16 bf16)
      const unsigned char* Vc = smem + 32768 + cur*16384;
      #pragma unroll
      for (int ct = 0; ct < 16; ++ct) {
        const int c = ct*16 + lr;
        const unsigned char* vrow = Vc + c*64;
        const int swv = (c & 3) << 4;
        #pragma unroll
        for (int kt2 = 0; kt2 < 2; ++kt2) {
          const s16x4 bf = *(const s16x4*)(vrow + ((kt2*32 + kb*8) ^ swv));
          acc[ct] = __builtin_amdgcn_mfma_f32_16x16x16bf16_1k(pa[kt2], bf, acc[ct], 0, 0, 0);
        }
      }
      __syncthreads();     // drains prefetch vmcnt + protects buffer swap
    }

    // ---- epilogue: h=1 writes OBt (fp32), h=0 combines + RMS + stores ----
    float lqv[4];
    #pragma unroll
    for (int r = 0; r < 4; ++r) lqv[r] = 1.f / __shfl(l_run, kb*4 + r);
    float* OB = (float*)smem;            // [256 c][32 f32], chunk-swizzled
    if (h == 1) {
      #pragma unroll
      for (int ct = 0; ct < 16; ++ct) {
        const int c = ct*16 + lr;
        const int byteo = (qt*64 + kb*16) ^ ((c & 7) << 4);
        f32x4 v = { acc[ct][0]*lqv[0], acc[ct][1]*lqv[1],
                    acc[ct][2]*lqv[2], acc[ct][3]*lqv[3] };
        *(f32x4*)((unsigned char*)OB + c*128 + byteo) = v;
      }
    }
    __syncthreads();
    if (h == 0) {
      float ss[4] = {0.f,0.f,0.f,0.f};
      #pragma unroll
      for (int ct = 0; ct < 16; ++ct) {
        const int c = ct*16 + lr;
        const int byteo = (qt*64 + kb*16) ^ ((c & 7) << 4);
        const f32x4 ob = *(const f32x4*)((const unsigned char*)OB + c*128 + byteo);
        #pragma unroll
        for (int r = 0; r < 4; ++r) {
          const float v = acc[ct][r]*lqv[r] - lambda_full*ob[r];
          acc[ct][r] = v; ss[r] += v*v;
        }
      }
      #pragma unroll
      for (int o = 8; o; o >>= 1) {
        #pragma unroll
        for (int r = 0; r < 4; ++r) ss[r] += __shfl_xor(ss[r], o);
      }
      const float fin = 1.f - lambda_init;
      float rms[4];
      #pragma unroll
      for (int r = 0; r < 4; ++r) rms[r] = rsqrtf(ss[r]*(1.f/256.f) + 1e-5f) * fin;
      #pragma unroll
      for (int ct = 0; ct < 16; ++ct) {
        const int c = ct*16 + lr;
        const float wv = wsub[c];
        #pragma unroll
        for (int r = 0; r < 4; ++r) {
          const long q = q0 + qt*16 + kb*4 + r;
          outp[(((long)b*SEQ + q)*8 + hp)*256 + c] = acc[ct][r]*rms[r]*wv;
        }
      }
    }
  }
}

extern "C" void kernel_launch(void* const* d_in, const int* in_sizes, int n_in,
                              void* d_out, int out_size, void* d_ws, size_t ws_size,
                              hipStream_t stream) {
  (void)in_sizes; (void)n_in; (void)out_size; (void)ws_size;
  const float lambda_init = (float)(0.8 - 0.6 * exp(-0.3 * (12 - 1)));
  u16* kb16 = (u16*)d_ws;                                // 16 MB
  u16* vt16 = (u16*)((char*)d_ws + (size_t)16*1024*1024); // 16 MB
  prep_kernel<<<dim3(1024), dim3(256), 0, stream>>>(
      (const float*)d_in[1], (const float*)d_in[2], kb16, vt16);
  diffattn_kernel<<<dim3(512), dim3(256), 0, stream>>>(
      (const float*)d_in[0], kb16, vt16,
      (const float*)d_in[3], (const float*)d_in[4], (const float*)d_in[5],
      (const float*)d_in[6], (const float*)d_in[7],
      (const int*)d_in[8],
      (float*)d_out, lambda_init);
}

// Round 4
// 297.292 us; speedup vs baseline: 2.0618x; 1.0808x over previous
//
#include <hip/hip_runtime.h>
#include <math.h>

namespace {
constexpr int SEQ = 2048;
constexpr int NH  = 16;
constexpr int DH  = 128;
constexpr int QB  = 64;          // q rows per block
constexpr int KBT = 32;          // k rows per iteration

typedef float f32x4 __attribute__((ext_vector_type(4)));
typedef short s16x8 __attribute__((ext_vector_type(8)));
typedef short s16x4 __attribute__((ext_vector_type(4)));
typedef unsigned short u16;

__device__ __forceinline__ u16 f2bf(float f) {
  unsigned u = __builtin_bit_cast(unsigned, f);
  return (u16)((u + 0x7fffu + ((u >> 16) & 1u)) >> 16);
}
__device__ __forceinline__ void gload16(const void* g, void* l) {
  __builtin_amdgcn_global_load_lds((const __attribute__((address_space(1))) void*)g,
                                   (__attribute__((address_space(3))) void*)l, 16, 0, 0);
}
}

// prep: K -> bf16 [b*8+hp][2h][k][128]; V -> bf16 transposed+k-permuted
// [b*8+hp][c=256][k'] where within each 32-k block, k' = perm(k):
// slot s=k'>>3 holds k = {s*4+r} U {16+s*4+r}  (feeds two 16x16x16 B-frags
// from one contiguous 16B read). One block per (b, head, ktile64).
__global__ __launch_bounds__(256) void prep_kernel(
    const float* __restrict__ kgl, const float* __restrict__ vg,
    u16* __restrict__ kb16, u16* __restrict__ vt16)
{
  __shared__ u16 vlds[64][132];
  const int tid = threadIdx.x, bid = blockIdx.x;
  const int kt = bid & 31, head = (bid >> 5) & 15, b = bid >> 9;
  const int k0 = kt * 64, hp = head >> 1, hh = head & 1;
  const float* ksrc = kgl + (((long)b*SEQ + k0)*NH + head)*DH;
  const float* vsrc = vg  + (((long)b*SEQ + k0)*NH + head)*DH;
  u16* kdst = kb16 + (((long)((b*8+hp)*2 + hh)*SEQ) + k0)*DH;
  #pragma unroll
  for (int i = 0; i < 8; ++i) {
    const int idx = tid + i*256, row = idx >> 5, c4 = idx & 31;
    const float4 v = *(const float4*)(ksrc + (long)row*(NH*DH) + c4*4);
    ushort4 pk = { f2bf(v.x), f2bf(v.y), f2bf(v.z), f2bf(v.w) };
    *(ushort4*)(kdst + row*DH + c4*4) = pk;
    const float4 w = *(const float4*)(vsrc + (long)row*(NH*DH) + c4*4);
    ushort4 pw = { f2bf(w.x), f2bf(w.y), f2bf(w.z), f2bf(w.w) };
    *(ushort4*)(&vlds[row][c4*4]) = pw;
  }
  __syncthreads();
  const int c = tid >> 1, half = tid & 1;
  u16* vdst = vt16 + (((long)(b*8+hp)*256) + hh*128 + c)*SEQ + k0 + half*32;
  #pragma unroll
  for (int j = 0; j < 8; ++j) {
    const int kb0 = (j >> 1)*4 + (j & 1)*16;   // k' = j*4 holds these k's
    ushort4 pk = { vlds[half*32 + kb0 + 0][c], vlds[half*32 + kb0 + 1][c],
                   vlds[half*32 + kb0 + 2][c], vlds[half*32 + kb0 + 3][c] };
    *(ushort4*)(vdst + j*4) = pk;
  }
}

// main: block = (pairing p, b, hp), QB=64. 4 waves = (h, qw); each wave
// computes 2 q-subtiles of 16 so every V b128 fragment feeds 4 MFMAs.
// LDS buf s: K [2h][32][256B] @ s*32768 (chunk^=(row&7));
//            V [64 R][16 chunks] @ +16384, chunk'=((c&3)<<2)|(slot^(R&3)).
__global__ __launch_bounds__(256, 2) void diffattn_kernel(
    const float* __restrict__ qg,
    const u16* __restrict__ kb16, const u16* __restrict__ vt16,
    const float* __restrict__ lq1, const float* __restrict__ lk1,
    const float* __restrict__ lq2, const float* __restrict__ lk2,
    const float* __restrict__ wsub, const int* __restrict__ amask,
    float* __restrict__ outp, float lambda_init)
{
  __shared__ __align__(16) unsigned char smem[65536];
  const int tid = threadIdx.x, lane = tid & 63, wid = tid >> 6;
  const int h = wid >> 1, qw = wid & 1, lr = lane & 15, kb = lane >> 4;
  const int bid = blockIdx.x;
  const int hp = bid & 7, b = (bid >> 3) & 1, p = bid >> 4;
  const int qtile = (p < 16) ? (31 - p) : (p - 16);   // pair sums = 33 iters
  const int q0 = qtile * QB;

  float s1 = lq1[lane]*lk1[lane] + lq1[lane+64]*lk1[lane+64];
  float s2 = lq2[lane]*lk2[lane] + lq2[lane+64]*lk2[lane+64];
  #pragma unroll
  for (int o = 32; o; o >>= 1) { s1 += __shfl_xor(s1, o); s2 += __shfl_xor(s2, o); }
  const float lambda_full = expf(s1) - expf(s2) + lambda_init;

  // staging offsets (u16 units); source pre-permuted so LDS dest is linear
  int koff[4], voff[4];
  #pragma unroll
  for (int i = 0; i < 4; ++i) {
    const int cid = tid + i*256;
    { const int hh = cid >> 9, row = (cid >> 4) & 31, ch = cid & 15;
      koff[i] = (hh*SEQ + row)*DH + (ch ^ (row & 7))*8; }
    { const int R = cid >> 4, ch = cid & 15;
      const int c = R*4 + (ch >> 2), sl = (ch & 3) ^ (R & 3);
      voff[i] = c*SEQ + sl*8; }
  }
  const u16* kbB = kb16 + (long)(b*8+hp)*2*SEQ*DH;
  const u16* vtB = vt16 + (long)(b*8+hp)*256*SEQ;

  const float qscale = 1.44269504088896f / sqrtf((float)DH);
  s16x8 qf[2][4];
  #pragma unroll
  for (int qs = 0; qs < 2; ++qs) {
    const int qrow = q0 + qw*32 + qs*16 + lr;
    const float* qp = qg + (((long)b*SEQ + qrow)*NH + hp*2 + h)*DH;
    #pragma unroll
    for (int ds = 0; ds < 4; ++ds) {
      const float4 a0 = *(const float4*)(qp + ds*32 + kb*8);
      const float4 a1 = *(const float4*)(qp + ds*32 + kb*8 + 4);
      s16x8 f;
      f[0]=(short)f2bf(a0.x*qscale); f[1]=(short)f2bf(a0.y*qscale);
      f[2]=(short)f2bf(a0.z*qscale); f[3]=(short)f2bf(a0.w*qscale);
      f[4]=(short)f2bf(a1.x*qscale); f[5]=(short)f2bf(a1.y*qscale);
      f[6]=(short)f2bf(a1.z*qscale); f[7]=(short)f2bf(a1.w*qscale);
      qf[qs][ds] = f;
    }
  }

  f32x4 acc[2][16];
  #pragma unroll
  for (int qs = 0; qs < 2; ++qs)
    #pragma unroll
    for (int i = 0; i < 16; ++i) acc[qs][i] = (f32x4){0.f,0.f,0.f,0.f};
  float m_run[2] = {-3.0e38f, -3.0e38f}, l_run[2] = {0.f, 0.f};
  const int nt = 2 * (qtile + 1);

  auto STAGE = [&](int k0s, int s) {
    unsigned char* dK = smem + s*32768;
    unsigned char* dV = dK + 16384;
    const u16* ksrc = kbB + (long)k0s*DH;
    const u16* vsrc = vtB + k0s;
    #pragma unroll
    for (int i = 0; i < 4; ++i) {
      gload16(ksrc + koff[i], dK + (tid + i*256)*16);
      gload16(vsrc + voff[i], dV + (tid + i*256)*16);
    }
  };

  STAGE(0, 0);
  __syncthreads();

  const int vofL = ((lr >> 2) << 8) + ((lr & 3) << 6) + ((kb ^ (lr >> 2)) << 4);
  const int swk = (lr & 7) << 4;

  for (int t = 0; t < nt; ++t) {
    const int cur = t & 1;
    if (t + 1 < nt) STAGE((t+1)*KBT, cur ^ 1);
    const int k0 = t * KBT;

    const int mi = amask[b*SEQ + k0 + (lane & 31)];
    const unsigned bm32 = (unsigned)__ballot(mi != 0 && lane < 32);

    // K fragments (read once, reused for both q-subtiles)
    const unsigned char* Kc = smem + cur*32768 + h*8192;
    s16x8 kfr[2][4];
    #pragma unroll
    for (int kt2 = 0; kt2 < 2; ++kt2) {
      const unsigned char* kr = Kc + (kt2*16 + lr)*256;
      #pragma unroll
      for (int ds = 0; ds < 4; ++ds)
        kfr[kt2][ds] = *(const s16x8*)(kr + ((ds*64 + kb*16) ^ swk));
    }

    // S^T = K . Q^T
    f32x4 st[2][2];
    #pragma unroll
    for (int qs = 0; qs < 2; ++qs)
      #pragma unroll
      for (int kt2 = 0; kt2 < 2; ++kt2) {
        f32x4 c = {0.f,0.f,0.f,0.f};
        #pragma unroll
        for (int ds = 0; ds < 4; ++ds)
          c = __builtin_amdgcn_mfma_f32_16x16x32_bf16(kfr[kt2][ds], qf[qs][ds], c, 0, 0, 0);
        st[qs][kt2] = c;
      }

    // online softmax per q-subtile (exp2 domain)
    float fac[2], pp[2][2][4];
    #pragma unroll
    for (int qs = 0; qs < 2; ++qs) {
      const int qmin = q0 + qw*32 + qs*16;
      const int qgrow = qmin + lr;
      const bool needmask = !((k0 + KBT - 1 <= qmin) && (bm32 == 0xffffffffu));
      float mx = -3.0e38f;
      #pragma unroll
      for (int kt2 = 0; kt2 < 2; ++kt2)
        #pragma unroll
        for (int r = 0; r < 4; ++r) {
          float sv = st[qs][kt2][r];
          if (needmask) {
            const int klo = kt2*16 + kb*4 + r;
            const bool ok = (k0 + klo <= qgrow) && ((bm32 >> klo) & 1u);
            sv = ok ? sv : -3.0e38f;
            st[qs][kt2][r] = sv;
          }
          mx = fmaxf(mx, sv);
        }
      mx = fmaxf(mx, __shfl_xor(mx, 16));
      mx = fmaxf(mx, __shfl_xor(mx, 32));
      const float mnew = fmaxf(m_run[qs], mx);
      fac[qs] = __builtin_amdgcn_exp2f(m_run[qs] - mnew);
      float lsum = 0.f;
      #pragma unroll
      for (int kt2 = 0; kt2 < 2; ++kt2)
        #pragma unroll
        for (int r = 0; r < 4; ++r) {
          const float pv = __builtin_amdgcn_exp2f(st[qs][kt2][r] - mnew);
          pp[qs][kt2][r] = pv; lsum += pv;
        }
      lsum += __shfl_xor(lsum, 16); lsum += __shfl_xor(lsum, 32);
      l_run[qs] = l_run[qs]*fac[qs] + lsum;
      m_run[qs] = mnew;
    }

    // rescale O only when some lane saw a new max (fac != 1)
    const bool nores = (fac[0] == 1.f) & (fac[1] == 1.f);
    if (!__all(nores)) {
      #pragma unroll
      for (int qs = 0; qs < 2; ++qs) {
        float fq[4];
        #pragma unroll
        for (int r = 0; r < 4; ++r) fq[r] = __shfl(fac[qs], kb*4 + r);
        #pragma unroll
        for (int ct = 0; ct < 16; ++ct) {
          acc[qs][ct][0]*=fq[0]; acc[qs][ct][1]*=fq[1];
          acc[qs][ct][2]*=fq[2]; acc[qs][ct][3]*=fq[3];
        }
      }
    }

    s16x4 pa[2][2];
    #pragma unroll
    for (int qs = 0; qs < 2; ++qs)
      #pragma unroll
      for (int kt2 = 0; kt2 < 2; ++kt2) {
        s16x4 tt = { (short)f2bf(pp[qs][kt2][0]), (short)f2bf(pp[qs][kt2][1]),
                     (short)f2bf(pp[qs][kt2][2]), (short)f2bf(pp[qs][kt2][3]) };
        pa[qs][kt2] = tt;
      }

    // O += P . V256 : one b128 V fragment feeds 4 MFMAs
    const unsigned char* Vc = smem + cur*32768 + 16384;
    #pragma unroll
    for (int ct = 0; ct < 16; ++ct) {
      const s16x8 vf = *(const s16x8*)(Vc + ct*1024 + vofL);
      const s16x4 v0 = { vf[0], vf[1], vf[2], vf[3] };
      const s16x4 v1 = { vf[4], vf[5], vf[6], vf[7] };
      #pragma unroll
      for (int qs = 0; qs < 2; ++qs) {
        acc[qs][ct] = __builtin_amdgcn_mfma_f32_16x16x16bf16_1k(pa[qs][0], v0, acc[qs][ct], 0, 0, 0);
        acc[qs][ct] = __builtin_amdgcn_mfma_f32_16x16x16bf16_1k(pa[qs][1], v1, acc[qs][ct], 0, 0, 0);
      }
    }
    __syncthreads();   // readers done before next prefetch overwrites; drains vmcnt
  }

  // epilogue: h=1 normalizes into LDS; h=0 combines, RMS-norms, stores
  float lqv[2][4];
  #pragma unroll
  for (int qs = 0; qs < 2; ++qs)
    #pragma unroll
    for (int r = 0; r < 4; ++r) lqv[qs][r] = 1.f / __shfl(l_run[qs], kb*4 + r);
  unsigned char* OB = smem + qw*32768;   // [256 c][128B], chunk ^= (c&7)
  if (h == 1) {
    #pragma unroll
    for (int qs = 0; qs < 2; ++qs)
      #pragma unroll
      for (int ct = 0; ct < 16; ++ct) {
        const int c = ct*16 + lr;
        const int byteo = (qs*64 + kb*16) ^ ((c & 7) << 4);
        f32x4 v = { acc[qs][ct][0]*lqv[qs][0], acc[qs][ct][1]*lqv[qs][1],
                    acc[qs][ct][2]*lqv[qs][2], acc[qs][ct][3]*lqv[qs][3] };
        *(f32x4*)(OB + c*128 + byteo) = v;
      }
  }
  __syncthreads();
  if (h == 0) {
    float ss[2][4] = {{0.f,0.f,0.f,0.f},{0.f,0.f,0.f,0.f}};
    #pragma unroll
    for (int qs = 0; qs < 2; ++qs)
      #pragma unroll
      for (int ct = 0; ct < 16; ++ct) {
        const int c = ct*16 + lr;
        const int byteo = (qs*64 + kb*16) ^ ((c & 7) << 4);
        const f32x4 ob = *(const f32x4*)(OB + c*128 + byteo);
        #pragma unroll
        for (int r = 0; r < 4; ++r) {
          const float v = acc[qs][ct][r]*lqv[qs][r] - lambda_full*ob[r];
          acc[qs][ct][r] = v; ss[qs][r] += v*v;
        }
      }
    #pragma unroll
    for (int o = 8; o; o >>= 1)
      #pragma unroll
      for (int qs = 0; qs < 2; ++qs)
        #pragma unroll
        for (int r = 0; r < 4; ++r) ss[qs][r] += __shfl_xor(ss[qs][r], o);
    const float fin = 1.f - lambda_init;
    float rms[2][4];
    #pragma unroll
    for (int qs = 0; qs < 2; ++qs)
      #pragma unroll
      for (int r = 0; r < 4; ++r)
        rms[qs][r] = rsqrtf(ss[qs][r]*(1.f/256.f) + 1e-5f) * fin;
    #pragma unroll
    for (int qs = 0; qs < 2; ++qs)
      #pragma unroll
      for (int ct = 0; ct < 16; ++ct) {
        const int c = ct*16 + lr;
        const float wv = wsub[c];
        #pragma unroll
        for (int r = 0; r < 4; ++r) {
          const long q = q0 + qw*32 + qs*16 + kb*4 + r;
          outp[(((long)b*SEQ + q)*8 + hp)*256 + c] = acc[qs][ct][r]*rms[qs][r]*wv;
        }
      }
  }
}

extern "C" void kernel_launch(void* const* d_in, const int* in_sizes, int n_in,
                              void* d_out, int out_size, void* d_ws, size_t ws_size,
                              hipStream_t stream) {
  (void)in_sizes; (void)n_in; (void)out_size; (void)ws_size;
  const float lambda_init = (float)(0.8 - 0.6 * exp(-0.3 * (12 - 1)));
  u16* kb16 = (u16*)d_ws;                                 // 16 MB
  u16* vt16 = (u16*)((char*)d_ws + (size_t)16*1024*1024); // 16 MB
  prep_kernel<<<dim3(1024), dim3(256), 0, stream>>>(
      (const float*)d_in[1], (const float*)d_in[2], kb16, vt16);
  diffattn_kernel<<<dim3(512), dim3(256), 0, stream>>>(
      (const float*)d_in[0], kb16, vt16,
      (const float*)d_in[3], (const float*)d_in[4], (const float*)d_in[5],
      (const float*)d_in[6], (const float*)d_in[7],
      (const int*)d_in[8],
      (float*)d_out, lambda_init);
}